// Round 1
// baseline (334.452 us; speedup 1.0000x reference)
//
#include <hip/hip_runtime.h>
#include <hip/hip_bf16.h>

// FastUpConvolution on MI355X — round 8: quadrant-major W rows, per-quadrant
// tap lists. Removes the 31% of MFMAs that multiplied zero-padded weight taps
// (q1/q2 use 6 of 9 taps, q3 uses 4; old interleaved row=co*4+q layout forced
// all 9 taps on every quadrant).
//
// R7 post-mortem: gemm 150us, MfmaUtil 44.3, VALU 17.5, HBM 12.8%, conflicts
// 0, occupancy 20.6 (LDS-limited, 2 blocks/CU). MFMA floor for issued work
// 62us -> stall-bound but also issuing 36 quadrant-taps where only 25 are
// useful. R8: row = q*256+co so each 128-row n-block is pure-quadrant; tap
// loop walks a per-q nibble-packed list. Block-tap units 72 -> 50 (-31%).
// Epilogue: lane's 4 acc regs = 4 consecutive co (one quadrant) -> scalar
// stores at fixed output parity offset; BN stats reduced per-reg.
//
// ws layout:
//   x_t   : bf16 [16][34][34][512]  @ 0          (18,939,904 B)
//   W_t   : bf16 [1024 rows][9*512] @ 18,939,904 ( 9,437,184 B)  row=q*256+co
//   bias  : f32  [1024]             @ 28,377,088 (     4,096 B)  row=q*256+co
//   stats : f32  [512] sum|sumsq    @ 28,381,184 (     2,048 B)

typedef unsigned short ushort_t;
typedef __attribute__((ext_vector_type(8))) short short8;
typedef __attribute__((ext_vector_type(4))) float floatx4;
typedef __attribute__((ext_vector_type(2))) float floatx2;
typedef __attribute__((ext_vector_type(4))) unsigned short u16x4;
typedef __attribute__((ext_vector_type(8))) unsigned short u16x8;
typedef __attribute__((ext_vector_type(4))) unsigned int u32x4;

#define XT_OFF    0u
#define WT_OFF    18939904u
#define BIAS_OFF  28377088u
#define STATS_OFF 28381184u

#define NSITES 204            // 6 rows x 34 cols X footprint, 128 B per site

#define ASYNC16(g, l) __builtin_amdgcn_global_load_lds( \
    (const __attribute__((address_space(1))) void*)(g), \
    (__attribute__((address_space(3))) void*)(l), 16, 0, 0)

__device__ __forceinline__ ushort_t f2bf(float f) {
  unsigned int u = __builtin_bit_cast(unsigned int, f);
  u += 0x7fffu + ((u >> 16) & 1u);   // RNE (values finite here)
  return (ushort_t)(u >> 16);
}

// ---------------------------------------------------------------- prep_x ---
// x[16][512][32][32] (f32) -> x_t[16][34][34][512] bf16, zero-padded NHWC.
__global__ __launch_bounds__(256) void prep_x(const float* __restrict__ x,
                                              ushort_t* __restrict__ xt) {
  const int b = blockIdx.x;
  const int n = b / 34, hp = b % 34;
  const int t = threadIdx.x;
  ushort_t* dst = xt + (size_t)(n * 34 + hp) * (34 * 512);
  if (hp == 0 || hp == 33) {
    u32x4 z = {0u, 0u, 0u, 0u};
    for (int i = t; i < 2176; i += 256) ((u32x4*)dst)[i] = z;
    return;
  }
  const int h = hp - 1;
  {
    u32x4 z = {0u, 0u, 0u, 0u};
    if (t < 64) ((u32x4*)dst)[t] = z;
    else if (t < 128) ((u32x4*)(dst + 33 * 512))[t - 64] = z;
  }
  __shared__ ushort_t lds[128 * 36];
  const size_t base = (size_t)n * 524288 + (size_t)h * 32;
  for (int ci0 = 0; ci0 < 512; ci0 += 128) {
    __syncthreads();
    {
      const int cil = t >> 3;
      const int w4 = (t & 7) << 2;
#pragma unroll
      for (int cc = 0; cc < 4; ++cc) {
        const int ci = cil + cc * 32;
        floatx4 v = *(const floatx4*)(x + base + (size_t)(ci0 + ci) * 1024 + w4);
        u16x4 hv;
#pragma unroll
        for (int j = 0; j < 4; ++j) hv[j] = f2bf(v[j]);
        *(u16x4*)&lds[ci * 36 + w4] = hv;
      }
    }
    __syncthreads();
    {
      const int w = t & 31;
      const int j8 = t >> 5;
#pragma unroll
      for (int cc2 = 0; cc2 < 2; ++cc2) {
        const int cil = cc2 * 64 + j8 * 8;
        u16x8 v;
#pragma unroll
        for (int j = 0; j < 8; ++j) v[j] = lds[(cil + j) * 36 + w];
        *(u16x8*)(dst + (w + 1) * 512 + ci0 + cil) = v;
      }
    }
  }
}

// ---------------------------------------------------------------- prep_w ---
// W_t[row=q*256+co][tap][ci] bf16; q0=3x3 q1=2x3 q2=3x2 q3=2x2; bias[row].
__global__ __launch_bounds__(256) void prep_w(
    const float* __restrict__ w1, const float* __restrict__ w2,
    const float* __restrict__ w3, const float* __restrict__ w4,
    const float* __restrict__ b1, const float* __restrict__ b2,
    const float* __restrict__ b3, const float* __restrict__ b4,
    ushort_t* __restrict__ wt, float* __restrict__ bias) {
  const int nout = blockIdx.x;
  const int q = nout >> 8, co = nout & 255;
  const int row = nout;              // q*256 + co (quadrant-major)
  const int t = threadIdx.x;
  const float* wsrc; const float* bsrc; int khl, kwl;
  if (q == 0)      { wsrc = w1; bsrc = b1; khl = 3; kwl = 3; }
  else if (q == 1) { wsrc = w2; bsrc = b2; khl = 2; kwl = 3; }
  else if (q == 2) { wsrc = w3; bsrc = b3; khl = 3; kwl = 2; }
  else             { wsrc = w4; bsrc = b4; khl = 2; kwl = 2; }
  if (t == 0) bias[row] = bsrc[co];
  ushort_t* dst = wt + (size_t)row * 4608;
  for (int tap = 0; tap < 9; ++tap) {
    const int dh = tap / 3, dw = tap % 3;
    const bool valid = (dh < khl) && (dw < kwl);
#pragma unroll
    for (int cc = 0; cc < 2; ++cc) {
      const int ci = cc * 256 + t;
      ushort_t v = 0;
      if (valid) v = f2bf(wsrc[(((size_t)co * 512 + ci) * khl + dh) * kwl + dw]);
      dst[tap * 512 + ci] = v;
    }
  }
}

// -------------------------------------------------------------- zero_stats --
__global__ void zero_stats(float* __restrict__ stats) {
  stats[threadIdx.x] = 0.f;   // 512 threads
}

// ------------------------------------------------------------------ gemm ---
// Block 128 m (4h x 32w) x 128 n (one quadrant); 4 waves 2x2, 4x4 frags of
// 16x16x32 bf16. K = 8 chunks x 64 ci x per-q tap list (9/6/6/4 taps).
// Per chunk: ASYNC16-stage X footprint (204 sites x 128 B) once + W(tap[0]);
// per tap: ASYNC16-stage W(tap[ti+1]) into the other buffer, 2 k-steps x
// 16 MFMA, one barrier. LDS unpadded, XOR-swizzled: 16B chunk c of row r
// lives at slot c^(r&7) -> DMA dest contiguous AND frag reads conflict-free.
__global__ __launch_bounds__(256) void gemm_kernel(
    const ushort_t* __restrict__ xt, const ushort_t* __restrict__ wt,
    const float* __restrict__ bias, float* __restrict__ out,
    float* __restrict__ stats) {
  __shared__ char ldsX[NSITES * 128];    // 26,112 B
  __shared__ char ldsW[2][128 * 128];    // 2 x 16,384 B
  const int tid = threadIdx.x;
  const int bx = blockIdx.x;
  const int bn = bx & 7, bm = bx >> 3;
  const int q = bn >> 1;                // quadrant of this n-block
  const int n0 = bn << 7;
  const int n_img = bm >> 3;
  const int h0p = (bm & 7) << 2;        // first padded x_t row of footprint
  const int wv = tid >> 6, lane = tid & 63;
  const int ri = lane & 15, kg = lane >> 4;
  const int wm = (wv & 1) << 6, wn = (wv >> 1) << 6;

  // per-quadrant tap schedule (nibble-packed, low nibble first)
  // q0 3x3: 0..8 | q1 2x3: 0,1,2,3,4,5 | q2 3x2: 0,1,3,4,6,7 | q3 2x2: 0,1,3,4
  const int ntaps = (q == 0) ? 9 : ((q == 3) ? 4 : 6);
  const unsigned long long tl =
      (q == 0) ? 0x876543210ull :
      (q == 1) ? 0x543210ull :
      (q == 2) ? 0x764310ull : 0x4310ull;

  // ---- staging pointer precompute (XOR swizzle at issue) ----
  // X: idx = p*256+tid over 1632 = 204 sites x 8 slots; slot holds chunk
  // c = slot ^ (site&7). LDS dest = ldsX + idx*16 (contiguous per wave).
  const char* xgp[7];
  char* xlp[7];
  {
    const char* xg = (const char*)(xt + (size_t)(n_img * 34 + h0p) * (34 * 512));
#pragma unroll
    for (int p = 0; p < 7; ++p) {
      const int idx = p * 256 + tid;
      const int site = idx >> 3, slot = idx & 7;
      const int c = slot ^ (site & 7);
      xgp[p] = xg + site * 1024 + (c << 4);
      xlp[p] = ldsX + idx * 16;
    }
  }
  // W: idx = p*256+tid over 1024 = 128 rows x 8 slots.
  const char* wgp[4];
  char* wlp0[4];
  char* wlp1[4];
#pragma unroll
  for (int p = 0; p < 4; ++p) {
    const int idx = p * 256 + tid;
    const int row = idx >> 3, slot = idx & 7;
    const int c = slot ^ (row & 7);
    wgp[p] = (const char*)wt + (size_t)(n0 + row) * 9216 + (c << 4);
    wlp0[p] = ldsW[0] + idx * 16;
    wlp1[p] = ldsW[1] + idx * 16;
  }

  floatx4 acc[4][4] = {};

  // fragment row/site indices
  int arow[4], bsite[4];
#pragma unroll
  for (int f = 0; f < 4; ++f) arow[f] = wn + (f << 4) + ri;
#pragma unroll
  for (int fj = 0; fj < 4; ++fj)
    bsite[fj] = ((wm >> 5) + (fj >> 1)) * 34 + ((fj & 1) << 4) + ri;

  for (int chunk = 0; chunk < 8; ++chunk) {
    const int cb = chunk << 7;
    // stage X footprint chunk + W(tap[0]=0) -> buf0 (prev readers done at the
    // barrier that ended the previous chunk's last tap)
#pragma unroll
    for (int p = 0; p < 6; ++p) ASYNC16(xgp[p] + cb, xlp[p]);
    if (tid < 96) ASYNC16(xgp[6] + cb, xlp[6]);   // tail: 1632 = 6*256+96
#pragma unroll
    for (int p = 0; p < 4; ++p) ASYNC16(wgp[p] + cb, wlp0[p]);
    __syncthreads();                     // drain vmcnt -> X + W0 visible
    for (int ti = 0; ti < ntaps; ++ti) {
      const int tap = (int)((tl >> (ti << 2)) & 15ull);
      // prefetch W(tap[ti+1]) into the other buffer (freed by last barrier)
      if (ti + 1 < ntaps) {
        const int ntap = (int)((tl >> ((ti + 1) << 2)) & 15ull);
        const int noff = (ntap << 10) + cb;
        if (ti & 1) {
#pragma unroll
          for (int p = 0; p < 4; ++p) ASYNC16(wgp[p] + noff, wlp0[p]);
        } else {
#pragma unroll
          for (int p = 0; p < 4; ++p) ASYNC16(wgp[p] + noff, wlp1[p]);
        }
      }
      const char* wb = ldsW[ti & 1];
      const int tsite = (tap / 3) * 34 + (tap % 3);   // X site offset of tap
#pragma unroll
      for (int ks = 0; ks < 2; ++ks) {
        const int c = (ks << 2) + kg;    // 16B chunk index within row
        short8 a4[4], b4[4];
#pragma unroll
        for (int f = 0; f < 4; ++f)
          a4[f] = *(const short8*)(wb + arow[f] * 128 +
                                   ((c ^ (arow[f] & 7)) << 4));
#pragma unroll
        for (int fj = 0; fj < 4; ++fj) {
          const int srow = bsite[fj] + tsite;   // shifted site; swizzle on it
          b4[fj] = *(const short8*)(ldsX + srow * 128 + ((c ^ (srow & 7)) << 4));
        }
#pragma unroll
        for (int fi = 0; fi < 4; ++fi)
#pragma unroll
          for (int fj = 0; fj < 4; ++fj)
            acc[fi][fj] = __builtin_amdgcn_mfma_f32_16x16x32_bf16(
                a4[fi], b4[fj], acc[fi][fj], 0, 0, 0);
      }
      __syncthreads();   // readers of wb & (last tap) X done; W(t+1) drained
    }
  }

  // ---- epilogue: +bias, per-quadrant parity writes, fused BN stats ----
  // D layout: col=lane&15 (m), row=quad*4+reg (n). Quadrant-major rows mean
  // reg j = consecutive co: co = cobase + j, all in quadrant q.
  // Output parity: q0->(ev,ev) q1->(odd,ev) q2->(ev,odd) q3->(odd,odd).
  const int quad = kg, colL = ri;
  const int dh = q & 1;                 // odd output row for q1,q3
  const int dw = q >> 1;                // odd output col for q2,q3
  const int pos_off = (dh << 6) + dw;
#pragma unroll
  for (int fi = 0; fi < 4; ++fi) {
    const int cobase = ((bn & 1) << 7) + wn + (fi << 4) + (quad << 2);
    const floatx4 bv = *(const floatx4*)(bias + (q << 8) + cobase);
    floatx4 sj = {};
    floatx4 s2j = {};
    float* ob = out + (((size_t)(n_img * 256 + cobase)) << 12) + pos_off;
#pragma unroll
    for (int fj = 0; fj < 4; ++fj) {
      const int mb = wm + (fj << 4) + colL;       // m within block
      const int h = h0p + (mb >> 5), w = mb & 31; // global h (0..31)
      const int off = (h << 7) + (w << 1);        // row 2h(+dh), col 2w(+dw)
#pragma unroll
      for (int j = 0; j < 4; ++j) {
        const float v = acc[fi][fj][j] + bv[j];
        sj[j] += v;
        s2j[j] += v * v;
        ob[((size_t)j << 12) + off] = v;
      }
    }
#pragma unroll
    for (int off = 1; off < 16; off <<= 1) {
#pragma unroll
      for (int j = 0; j < 4; ++j) {
        sj[j] += __shfl_xor(sj[j], off);
        s2j[j] += __shfl_xor(s2j[j], off);
      }
    }
    if (colL == 0) {
#pragma unroll
      for (int j = 0; j < 4; ++j) {
        atomicAdd(&stats[cobase + j], sj[j]);
        atomicAdd(&stats[256 + cobase + j], s2j[j]);
      }
    }
  }
}

// -------------------------------------------------------------- bn_apply ---
__global__ __launch_bounds__(256) void bn_apply(
    float* __restrict__ y, const float* __restrict__ stats,
    const float* __restrict__ gamma, const float* __restrict__ beta) {
  const int b = blockIdx.x;
  const int co = b & 255;
  const int t = threadIdx.x;
  const float mean = stats[co] * (1.f / 65536.f);
  const float var = stats[256 + co] * (1.f / 65536.f) - mean * mean;
  const float rstd = rsqrtf(var + 1e-5f);
  const float scale = rstd * gamma[co];
  const float shift = beta[co] - mean * scale;
  float* p = y + (size_t)b * 4096;
#pragma unroll
  for (int it = 0; it < 4; ++it) {
    floatx4* q = (floatx4*)(p + (it * 256 + t) * 4);
    floatx4 v = *q;
#pragma unroll
    for (int e = 0; e < 4; ++e) v[e] = fmaxf(v[e] * scale + shift, 0.f);
    *q = v;
  }
}

// ---------------------------------------------------------------- launch ---
extern "C" void kernel_launch(void* const* d_in, const int* in_sizes, int n_in,
                              void* d_out, int out_size, void* d_ws,
                              size_t ws_size, hipStream_t stream) {
  const float* x  = (const float*)d_in[0];
  const float* w1 = (const float*)d_in[1];
  const float* b1 = (const float*)d_in[2];
  const float* w2 = (const float*)d_in[3];
  const float* b2 = (const float*)d_in[4];
  const float* w3 = (const float*)d_in[5];
  const float* b3 = (const float*)d_in[6];
  const float* w4 = (const float*)d_in[7];
  const float* b4 = (const float*)d_in[8];
  const float* gamma = (const float*)d_in[9];
  const float* beta  = (const float*)d_in[10];
  float* out = (float*)d_out;

  char* ws = (char*)d_ws;
  ushort_t* xt   = (ushort_t*)(ws + XT_OFF);
  ushort_t* wt   = (ushort_t*)(ws + WT_OFF);
  float*    bias = (float*)(ws + BIAS_OFF);
  float*    st   = (float*)(ws + STATS_OFF);

  zero_stats<<<1, 512, 0, stream>>>(st);
  prep_x<<<16 * 34, 256, 0, stream>>>(x, xt);
  prep_w<<<1024, 256, 0, stream>>>(w1, w2, w3, w4, b1, b2, b3, b4, wt, bias);
  gemm_kernel<<<1024, 256, 0, stream>>>(xt, wt, bias, out, st);
  bn_apply<<<4096, 256, 0, stream>>>(out, st, gamma, beta);
}

// Round 2
// 312.244 us; speedup vs baseline: 1.0711x; 1.0711x over previous
//
#include <hip/hip_runtime.h>
#include <hip/hip_bf16.h>

// FastUpConvolution on MI355X — round 9: pair-interleaved W rows.
// row' = co*2 + s with pair P0=(q0 s0, q2 s1) rows 0..511, P1=(q1,q3) rows
// 512..1023. Each n-block is one pair -> reg pair (j0,j1) = same co, two
// col parities -> dense floatx2 pixel-shuffle writes (R7's proven epilogue),
// while P1 blocks run only 6 taps (union of 2x3 and 2x2) vs 9.
// Segments 72 -> 60 per m-block (-17%).
//
// R8 post-mortem: quadrant-major rows cut MFMA to the 43us floor as predicted
// but single-parity scatter writes doubled WRITE_SIZE (66.5->139 GB-KB, no
// cross-block L2 merge) and added ~96us of store stall. The interleaved row
// layout's dense 2x2 write is structural -- keep it at pair granularity.
//
// ws layout:
//   x_t   : bf16 [16][34][34][512]  @ 0          (18,939,904 B)
//   W_t   : bf16 [1024 rows][9*512] @ 18,939,904 ( 9,437,184 B)  row=pair-ilv
//   bias  : f32  [1024]             @ 28,377,088 (     4,096 B)  row=pair-ilv
//   stats : f32  [512] sum|sumsq    @ 28,381,184 (     2,048 B)

typedef unsigned short ushort_t;
typedef __attribute__((ext_vector_type(8))) short short8;
typedef __attribute__((ext_vector_type(4))) float floatx4;
typedef __attribute__((ext_vector_type(2))) float floatx2;
typedef __attribute__((ext_vector_type(4))) unsigned short u16x4;
typedef __attribute__((ext_vector_type(8))) unsigned short u16x8;
typedef __attribute__((ext_vector_type(4))) unsigned int u32x4;

#define XT_OFF    0u
#define WT_OFF    18939904u
#define BIAS_OFF  28377088u
#define STATS_OFF 28381184u

#define NSITES 204            // 6 rows x 34 cols X footprint, 128 B per site

#define ASYNC16(g, l) __builtin_amdgcn_global_load_lds( \
    (const __attribute__((address_space(1))) void*)(g), \
    (__attribute__((address_space(3))) void*)(l), 16, 0, 0)

__device__ __forceinline__ ushort_t f2bf(float f) {
  unsigned int u = __builtin_bit_cast(unsigned int, f);
  u += 0x7fffu + ((u >> 16) & 1u);   // RNE (values finite here)
  return (ushort_t)(u >> 16);
}

// ---------------------------------------------------------------- prep_x ---
// x[16][512][32][32] (f32) -> x_t[16][34][34][512] bf16, zero-padded NHWC.
__global__ __launch_bounds__(256) void prep_x(const float* __restrict__ x,
                                              ushort_t* __restrict__ xt) {
  const int b = blockIdx.x;
  const int n = b / 34, hp = b % 34;
  const int t = threadIdx.x;
  ushort_t* dst = xt + (size_t)(n * 34 + hp) * (34 * 512);
  if (hp == 0 || hp == 33) {
    u32x4 z = {0u, 0u, 0u, 0u};
    for (int i = t; i < 2176; i += 256) ((u32x4*)dst)[i] = z;
    return;
  }
  const int h = hp - 1;
  {
    u32x4 z = {0u, 0u, 0u, 0u};
    if (t < 64) ((u32x4*)dst)[t] = z;
    else if (t < 128) ((u32x4*)(dst + 33 * 512))[t - 64] = z;
  }
  __shared__ ushort_t lds[128 * 36];
  const size_t base = (size_t)n * 524288 + (size_t)h * 32;
  for (int ci0 = 0; ci0 < 512; ci0 += 128) {
    __syncthreads();
    {
      const int cil = t >> 3;
      const int w4 = (t & 7) << 2;
#pragma unroll
      for (int cc = 0; cc < 4; ++cc) {
        const int ci = cil + cc * 32;
        floatx4 v = *(const floatx4*)(x + base + (size_t)(ci0 + ci) * 1024 + w4);
        u16x4 hv;
#pragma unroll
        for (int j = 0; j < 4; ++j) hv[j] = f2bf(v[j]);
        *(u16x4*)&lds[ci * 36 + w4] = hv;
      }
    }
    __syncthreads();
    {
      const int w = t & 31;
      const int j8 = t >> 5;
#pragma unroll
      for (int cc2 = 0; cc2 < 2; ++cc2) {
        const int cil = cc2 * 64 + j8 * 8;
        u16x8 v;
#pragma unroll
        for (int j = 0; j < 8; ++j) v[j] = lds[(cil + j) * 36 + w];
        *(u16x8*)(dst + (w + 1) * 512 + ci0 + cil) = v;
      }
    }
  }
}

// ---------------------------------------------------------------- prep_w ---
// W_t[row'][tap][ci] bf16; row' = ((q&1)<<9) + co*2 + (q>>1):
//   P0 rows 0..511  : q0 (3x3) at s=0, q2 (3x2) at s=1   (even output rows)
//   P1 rows 512..1023: q1 (2x3) at s=0, q3 (2x2) at s=1  (odd output rows)
// Invalid taps zero-filled (q2: dw==2; q1: dh==2; q3: dh==2|dw==2).
__global__ __launch_bounds__(256) void prep_w(
    const float* __restrict__ w1, const float* __restrict__ w2,
    const float* __restrict__ w3, const float* __restrict__ w4,
    const float* __restrict__ b1, const float* __restrict__ b2,
    const float* __restrict__ b3, const float* __restrict__ b4,
    ushort_t* __restrict__ wt, float* __restrict__ bias) {
  const int nout = blockIdx.x;
  const int q = nout >> 8, co = nout & 255;
  const int row = ((q & 1) << 9) + (co << 1) + (q >> 1);   // pair-interleaved
  const int t = threadIdx.x;
  const float* wsrc; const float* bsrc; int khl, kwl;
  if (q == 0)      { wsrc = w1; bsrc = b1; khl = 3; kwl = 3; }
  else if (q == 1) { wsrc = w2; bsrc = b2; khl = 2; kwl = 3; }
  else if (q == 2) { wsrc = w3; bsrc = b3; khl = 3; kwl = 2; }
  else             { wsrc = w4; bsrc = b4; khl = 2; kwl = 2; }
  if (t == 0) bias[row] = bsrc[co];
  ushort_t* dst = wt + (size_t)row * 4608;
  for (int tap = 0; tap < 9; ++tap) {
    const int dh = tap / 3, dw = tap % 3;
    const bool valid = (dh < khl) && (dw < kwl);
#pragma unroll
    for (int cc = 0; cc < 2; ++cc) {
      const int ci = cc * 256 + t;
      ushort_t v = 0;
      if (valid) v = f2bf(wsrc[(((size_t)co * 512 + ci) * khl + dh) * kwl + dw]);
      dst[tap * 512 + ci] = v;
    }
  }
}

// -------------------------------------------------------------- zero_stats --
__global__ void zero_stats(float* __restrict__ stats) {
  stats[threadIdx.x] = 0.f;   // 512 threads
}

// ------------------------------------------------------------------ gemm ---
// Block 128 m (4h x 32w) x 128 n (one quadrant-pair); 4 waves 2x2, 4x4 frags
// of 16x16x32 bf16. K = 8 chunks x 64 ci x pair tap count (P0: 9, P1: 6).
// Per chunk: ASYNC16-stage X footprint (204 sites x 128 B) once + W(tap0);
// per tap: ASYNC16-stage W(tap+1) into the other buffer, 2 k-steps x 16 MFMA,
// one barrier. LDS unpadded, XOR-swizzled: 16B chunk c of row r lives at
// slot c^(r&7) -> DMA dest contiguous AND frag reads conflict-free.
__global__ __launch_bounds__(256) void gemm_kernel(
    const ushort_t* __restrict__ xt, const ushort_t* __restrict__ wt,
    const float* __restrict__ bias, float* __restrict__ out,
    float* __restrict__ stats) {
  __shared__ char ldsX[NSITES * 128];    // 26,112 B
  __shared__ char ldsW[2][128 * 128];    // 2 x 16,384 B
  const int tid = threadIdx.x;
  const int bx = blockIdx.x;
  const int bn = bx & 7, bm = bx >> 3;
  const int n0 = bn << 7;
  const int n_img = bm >> 3;
  const int h0p = (bm & 7) << 2;        // first padded x_t row of footprint
  const int wv = tid >> 6, lane = tid & 63;
  const int ri = lane & 15, kg = lane >> 4;
  const int wm = (wv & 1) << 6, wn = (wv >> 1) << 6;

  // pair tap count: P0 (bn<4) = union(3x3,3x2) = 9 taps; P1 = union(2x3,2x2)
  // = taps 0..5 (q1's full set; q3 zero-filled on taps 2,5).
  const int ntaps = (bn < 4) ? 9 : 6;

  // ---- staging pointer precompute (XOR swizzle at issue) ----
  // X: idx = p*256+tid over 1632 = 204 sites x 8 slots; slot holds chunk
  // c = slot ^ (site&7). LDS dest = ldsX + idx*16 (contiguous per wave).
  const char* xgp[7];
  char* xlp[7];
  {
    const char* xg = (const char*)(xt + (size_t)(n_img * 34 + h0p) * (34 * 512));
#pragma unroll
    for (int p = 0; p < 7; ++p) {
      const int idx = p * 256 + tid;
      const int site = idx >> 3, slot = idx & 7;
      const int c = slot ^ (site & 7);
      xgp[p] = xg + site * 1024 + (c << 4);
      xlp[p] = ldsX + idx * 16;
    }
  }
  // W: idx = p*256+tid over 1024 = 128 rows x 8 slots.
  const char* wgp[4];
  char* wlp0[4];
  char* wlp1[4];
#pragma unroll
  for (int p = 0; p < 4; ++p) {
    const int idx = p * 256 + tid;
    const int row = idx >> 3, slot = idx & 7;
    const int c = slot ^ (row & 7);
    wgp[p] = (const char*)wt + (size_t)(n0 + row) * 9216 + (c << 4);
    wlp0[p] = ldsW[0] + idx * 16;
    wlp1[p] = ldsW[1] + idx * 16;
  }

  floatx4 acc[4][4] = {};

  // fragment row/site indices
  int arow[4], bsite[4];
#pragma unroll
  for (int f = 0; f < 4; ++f) arow[f] = wn + (f << 4) + ri;
#pragma unroll
  for (int fj = 0; fj < 4; ++fj)
    bsite[fj] = ((wm >> 5) + (fj >> 1)) * 34 + ((fj & 1) << 4) + ri;

  for (int chunk = 0; chunk < 8; ++chunk) {
    const int cb = chunk << 7;
    // stage X footprint chunk + W(tap0) -> buf0 (prev readers done at the
    // barrier that ended the previous chunk's last tap)
#pragma unroll
    for (int p = 0; p < 6; ++p) ASYNC16(xgp[p] + cb, xlp[p]);
    if (tid < 96) ASYNC16(xgp[6] + cb, xlp[6]);   // tail: 1632 = 6*256+96
#pragma unroll
    for (int p = 0; p < 4; ++p) ASYNC16(wgp[p] + cb, wlp0[p]);
    __syncthreads();                     // drain vmcnt -> X + W0 visible
    for (int tap = 0; tap < ntaps; ++tap) {
      // prefetch W(tap+1) into the other buffer (freed by last barrier)
      if (tap + 1 < ntaps) {
        const int noff = ((tap + 1) << 10) + cb;
        if (tap & 1) {
#pragma unroll
          for (int p = 0; p < 4; ++p) ASYNC16(wgp[p] + noff, wlp0[p]);
        } else {
#pragma unroll
          for (int p = 0; p < 4; ++p) ASYNC16(wgp[p] + noff, wlp1[p]);
        }
      }
      const char* wb = ldsW[tap & 1];
      const int tsite = (tap / 3) * 34 + (tap % 3);   // X site offset of tap
#pragma unroll
      for (int ks = 0; ks < 2; ++ks) {
        const int c = (ks << 2) + kg;    // 16B chunk index within row
        short8 a4[4], b4[4];
#pragma unroll
        for (int f = 0; f < 4; ++f)
          a4[f] = *(const short8*)(wb + arow[f] * 128 +
                                   ((c ^ (arow[f] & 7)) << 4));
#pragma unroll
        for (int fj = 0; fj < 4; ++fj) {
          const int srow = bsite[fj] + tsite;   // shifted site; swizzle on it
          b4[fj] = *(const short8*)(ldsX + srow * 128 + ((c ^ (srow & 7)) << 4));
        }
#pragma unroll
        for (int fi = 0; fi < 4; ++fi)
#pragma unroll
          for (int fj = 0; fj < 4; ++fj)
            acc[fi][fj] = __builtin_amdgcn_mfma_f32_16x16x32_bf16(
                a4[fi], b4[fj], acc[fi][fj], 0, 0, 0);
      }
      __syncthreads();   // readers of wb & (last tap) X done; W(t+1) drained
    }
  }

  // ---- epilogue: +bias, dense 2x2 pixel-shuffle writes, fused BN stats ----
  // D layout: col=lane&15 (m), row=quad*4+reg (n). Pair-interleaved rows:
  // frag n-row r = kg*4 + j -> co = (r_global & 511)>>1, s = j&1.
  // (j0,j1) = same co, cols 2w/2w+1 -> contiguous floatx2; (j2,j3) = co+1.
  // Output row parity: P0 (bn<4) -> even rows; P1 -> odd rows.
  const int quad = kg, colL = ri;
  const int dh6 = (bn >> 2) << 6;       // +64 floats for odd output rows
#pragma unroll
  for (int fi = 0; fi < 4; ++fi) {
    const int rbase = n0 + wn + (fi << 4) + (quad << 2);   // global row', j=0..3
    const floatx4 bv = *(const floatx4*)(bias + rbase);
    const int co = (rbase & 511) >> 1;
    float sA = 0.f, s2A = 0.f, sB = 0.f, s2B = 0.f;
    float* ob = out + (((size_t)(n_img * 256 + co)) << 12) + dh6;
#pragma unroll
    for (int fj = 0; fj < 4; ++fj) {
      const int mb = wm + (fj << 4) + colL;       // m within block
      const int h = h0p + (mb >> 5), w = mb & 31; // global h (0..31)
      const float v0 = acc[fi][fj][0] + bv[0];
      const float v1 = acc[fi][fj][1] + bv[1];
      const float v2 = acc[fi][fj][2] + bv[2];
      const float v3 = acc[fi][fj][3] + bv[3];
      sA += v0 + v1;
      s2A += v0 * v0 + v1 * v1;
      sB += v2 + v3;
      s2B += v2 * v2 + v3 * v3;
      float* p = ob + (h << 7) + (w << 1);        // row 2h(+dh), col 2w
      floatx2 eA = {v0, v1};
      floatx2 eB = {v2, v3};
      *(floatx2*)p = eA;                           // co
      *(floatx2*)(p + 4096) = eB;                  // co+1
    }
#pragma unroll
    for (int off = 1; off < 16; off <<= 1) {
      sA += __shfl_xor(sA, off);
      s2A += __shfl_xor(s2A, off);
      sB += __shfl_xor(sB, off);
      s2B += __shfl_xor(s2B, off);
    }
    if (colL == 0) {
      atomicAdd(&stats[co], sA);
      atomicAdd(&stats[256 + co], s2A);
      atomicAdd(&stats[co + 1], sB);
      atomicAdd(&stats[256 + co + 1], s2B);
    }
  }
}

// -------------------------------------------------------------- bn_apply ---
__global__ __launch_bounds__(256) void bn_apply(
    float* __restrict__ y, const float* __restrict__ stats,
    const float* __restrict__ gamma, const float* __restrict__ beta) {
  const int b = blockIdx.x;
  const int co = b & 255;
  const int t = threadIdx.x;
  const float mean = stats[co] * (1.f / 65536.f);
  const float var = stats[256 + co] * (1.f / 65536.f) - mean * mean;
  const float rstd = rsqrtf(var + 1e-5f);
  const float scale = rstd * gamma[co];
  const float shift = beta[co] - mean * scale;
  float* p = y + (size_t)b * 4096;
#pragma unroll
  for (int it = 0; it < 4; ++it) {
    floatx4* q = (floatx4*)(p + (it * 256 + t) * 4);
    floatx4 v = *q;
#pragma unroll
    for (int e = 0; e < 4; ++e) v[e] = fmaxf(v[e] * scale + shift, 0.f);
    *q = v;
  }
}

// ---------------------------------------------------------------- launch ---
extern "C" void kernel_launch(void* const* d_in, const int* in_sizes, int n_in,
                              void* d_out, int out_size, void* d_ws,
                              size_t ws_size, hipStream_t stream) {
  const float* x  = (const float*)d_in[0];
  const float* w1 = (const float*)d_in[1];
  const float* b1 = (const float*)d_in[2];
  const float* w2 = (const float*)d_in[3];
  const float* b2 = (const float*)d_in[4];
  const float* w3 = (const float*)d_in[5];
  const float* b3 = (const float*)d_in[6];
  const float* w4 = (const float*)d_in[7];
  const float* b4 = (const float*)d_in[8];
  const float* gamma = (const float*)d_in[9];
  const float* beta  = (const float*)d_in[10];
  float* out = (float*)d_out;

  char* ws = (char*)d_ws;
  ushort_t* xt   = (ushort_t*)(ws + XT_OFF);
  ushort_t* wt   = (ushort_t*)(ws + WT_OFF);
  float*    bias = (float*)(ws + BIAS_OFF);
  float*    st   = (float*)(ws + STATS_OFF);

  zero_stats<<<1, 512, 0, stream>>>(st);
  prep_x<<<16 * 34, 256, 0, stream>>>(x, xt);
  prep_w<<<1024, 256, 0, stream>>>(w1, w2, w3, w4, b1, b2, b3, b4, wt, bias);
  gemm_kernel<<<1024, 256, 0, stream>>>(xt, wt, bias, out, st);
  bn_apply<<<4096, 256, 0, stream>>>(out, st, gamma, beta);
}

// Round 3
// 280.101 us; speedup vs baseline: 1.1940x; 1.1148x over previous
//
#include <hip/hip_runtime.h>
#include <hip/hip_bf16.h>

// FastUpConvolution on MI355X — round 10: R9's pair-interleaved layout +
// compile-time tap counts (template<NTAPS>, wave-uniform dispatch at entry).
//
// R9 post-mortem: dense floatx2 writes restored (WRITE 139->67.5 GB-KB) and
// MFMA busy hit the 52us floor, but the runtime-bounded tap loop (ntaps =
// bn<4?9:6) killed unrolling: no static double-buffer select, no cross-tap
// ds_read pipelining -> non-MFMA path 84->137us, MfmaUtil 44->28. R10 makes
// NTAPS a template parameter (bn<4 -> 9, else 6); LDS declared in the kernel
// and passed by pointer so both instantiations share one 58,880B allocation.
//
// ws layout:
//   x_t   : bf16 [16][34][34][512]  @ 0          (18,939,904 B)
//   W_t   : bf16 [1024 rows][9*512] @ 18,939,904 ( 9,437,184 B)  row=pair-ilv
//   bias  : f32  [1024]             @ 28,377,088 (     4,096 B)  row=pair-ilv
//   stats : f32  [512] sum|sumsq    @ 28,381,184 (     2,048 B)
//
// Row layout: row' = ((q&1)<<9) + co*2 + (q>>1):
//   P0 rows 0..511   : q0 (3x3) s=0, q2 (3x2) s=1  -> even output rows, 9 taps
//   P1 rows 512..1023: q1 (2x3) s=0, q3 (2x2) s=1  -> odd output rows, 6 taps

typedef unsigned short ushort_t;
typedef __attribute__((ext_vector_type(8))) short short8;
typedef __attribute__((ext_vector_type(4))) float floatx4;
typedef __attribute__((ext_vector_type(2))) float floatx2;
typedef __attribute__((ext_vector_type(4))) unsigned short u16x4;
typedef __attribute__((ext_vector_type(8))) unsigned short u16x8;
typedef __attribute__((ext_vector_type(4))) unsigned int u32x4;

#define XT_OFF    0u
#define WT_OFF    18939904u
#define BIAS_OFF  28377088u
#define STATS_OFF 28381184u

#define NSITES 204            // 6 rows x 34 cols X footprint, 128 B per site

#define ASYNC16(g, l) __builtin_amdgcn_global_load_lds( \
    (const __attribute__((address_space(1))) void*)(g), \
    (__attribute__((address_space(3))) void*)(l), 16, 0, 0)

__device__ __forceinline__ ushort_t f2bf(float f) {
  unsigned int u = __builtin_bit_cast(unsigned int, f);
  u += 0x7fffu + ((u >> 16) & 1u);   // RNE (values finite here)
  return (ushort_t)(u >> 16);
}

// ---------------------------------------------------------------- prep_x ---
// x[16][512][32][32] (f32) -> x_t[16][34][34][512] bf16, zero-padded NHWC.
__global__ __launch_bounds__(256) void prep_x(const float* __restrict__ x,
                                              ushort_t* __restrict__ xt) {
  const int b = blockIdx.x;
  const int n = b / 34, hp = b % 34;
  const int t = threadIdx.x;
  ushort_t* dst = xt + (size_t)(n * 34 + hp) * (34 * 512);
  if (hp == 0 || hp == 33) {
    u32x4 z = {0u, 0u, 0u, 0u};
    for (int i = t; i < 2176; i += 256) ((u32x4*)dst)[i] = z;
    return;
  }
  const int h = hp - 1;
  {
    u32x4 z = {0u, 0u, 0u, 0u};
    if (t < 64) ((u32x4*)dst)[t] = z;
    else if (t < 128) ((u32x4*)(dst + 33 * 512))[t - 64] = z;
  }
  __shared__ ushort_t lds[128 * 36];
  const size_t base = (size_t)n * 524288 + (size_t)h * 32;
  for (int ci0 = 0; ci0 < 512; ci0 += 128) {
    __syncthreads();
    {
      const int cil = t >> 3;
      const int w4 = (t & 7) << 2;
#pragma unroll
      for (int cc = 0; cc < 4; ++cc) {
        const int ci = cil + cc * 32;
        floatx4 v = *(const floatx4*)(x + base + (size_t)(ci0 + ci) * 1024 + w4);
        u16x4 hv;
#pragma unroll
        for (int j = 0; j < 4; ++j) hv[j] = f2bf(v[j]);
        *(u16x4*)&lds[ci * 36 + w4] = hv;
      }
    }
    __syncthreads();
    {
      const int w = t & 31;
      const int j8 = t >> 5;
#pragma unroll
      for (int cc2 = 0; cc2 < 2; ++cc2) {
        const int cil = cc2 * 64 + j8 * 8;
        u16x8 v;
#pragma unroll
        for (int j = 0; j < 8; ++j) v[j] = lds[(cil + j) * 36 + w];
        *(u16x8*)(dst + (w + 1) * 512 + ci0 + cil) = v;
      }
    }
  }
}

// ---------------------------------------------------------------- prep_w ---
// W_t[row'][tap][ci] bf16; row' = ((q&1)<<9) + co*2 + (q>>1).
// Invalid taps zero-filled (q2: dw==2; q1: dh==2; q3: dh==2|dw==2).
__global__ __launch_bounds__(256) void prep_w(
    const float* __restrict__ w1, const float* __restrict__ w2,
    const float* __restrict__ w3, const float* __restrict__ w4,
    const float* __restrict__ b1, const float* __restrict__ b2,
    const float* __restrict__ b3, const float* __restrict__ b4,
    ushort_t* __restrict__ wt, float* __restrict__ bias) {
  const int nout = blockIdx.x;
  const int q = nout >> 8, co = nout & 255;
  const int row = ((q & 1) << 9) + (co << 1) + (q >> 1);   // pair-interleaved
  const int t = threadIdx.x;
  const float* wsrc; const float* bsrc; int khl, kwl;
  if (q == 0)      { wsrc = w1; bsrc = b1; khl = 3; kwl = 3; }
  else if (q == 1) { wsrc = w2; bsrc = b2; khl = 2; kwl = 3; }
  else if (q == 2) { wsrc = w3; bsrc = b3; khl = 3; kwl = 2; }
  else             { wsrc = w4; bsrc = b4; khl = 2; kwl = 2; }
  if (t == 0) bias[row] = bsrc[co];
  ushort_t* dst = wt + (size_t)row * 4608;
  for (int tap = 0; tap < 9; ++tap) {
    const int dh = tap / 3, dw = tap % 3;
    const bool valid = (dh < khl) && (dw < kwl);
#pragma unroll
    for (int cc = 0; cc < 2; ++cc) {
      const int ci = cc * 256 + t;
      ushort_t v = 0;
      if (valid) v = f2bf(wsrc[(((size_t)co * 512 + ci) * khl + dh) * kwl + dw]);
      dst[tap * 512 + ci] = v;
    }
  }
}

// -------------------------------------------------------------- zero_stats --
__global__ void zero_stats(float* __restrict__ stats) {
  stats[threadIdx.x] = 0.f;   // 512 threads
}

// ------------------------------------------------------------- gemm body ---
// Block 128 m (4h x 32w) x 128 n (one quadrant-pair); 4 waves 2x2, 4x4 frags
// of 16x16x32 bf16. K = 8 chunks x 64 ci x NTAPS (compile-time: P0 9, P1 6).
// Per chunk: ASYNC16-stage X footprint (204 sites x 128 B) once + W(tap0);
// per tap: ASYNC16-stage W(tap+1) into the other buffer, 2 k-steps x 16 MFMA,
// one barrier. LDS unpadded, XOR-swizzled: 16B chunk c of row r lives at
// slot c^(r&7) -> DMA dest contiguous AND frag reads conflict-free.
template <int NTAPS>
__device__ __forceinline__ void gemm_body(
    const ushort_t* __restrict__ xt, const ushort_t* __restrict__ wt,
    const float* __restrict__ bias, float* __restrict__ out,
    float* __restrict__ stats, char* ldsX, char* ldsW0, char* ldsW1) {
  const int tid = threadIdx.x;
  const int bx = blockIdx.x;
  const int bn = bx & 7, bm = bx >> 3;
  const int n0 = bn << 7;
  const int n_img = bm >> 3;
  const int h0p = (bm & 7) << 2;        // first padded x_t row of footprint
  const int wv = tid >> 6, lane = tid & 63;
  const int ri = lane & 15, kg = lane >> 4;
  const int wm = (wv & 1) << 6, wn = (wv >> 1) << 6;

  // ---- staging pointer precompute (XOR swizzle at issue) ----
  // X: idx = p*256+tid over 1632 = 204 sites x 8 slots; slot holds chunk
  // c = slot ^ (site&7). LDS dest = ldsX + idx*16 (contiguous per wave).
  const char* xgp[7];
  char* xlp[7];
  {
    const char* xg = (const char*)(xt + (size_t)(n_img * 34 + h0p) * (34 * 512));
#pragma unroll
    for (int p = 0; p < 7; ++p) {
      const int idx = p * 256 + tid;
      const int site = idx >> 3, slot = idx & 7;
      const int c = slot ^ (site & 7);
      xgp[p] = xg + site * 1024 + (c << 4);
      xlp[p] = ldsX + idx * 16;
    }
  }
  // W: idx = p*256+tid over 1024 = 128 rows x 8 slots.
  const char* wgp[4];
  char* wlp0[4];
  char* wlp1[4];
#pragma unroll
  for (int p = 0; p < 4; ++p) {
    const int idx = p * 256 + tid;
    const int row = idx >> 3, slot = idx & 7;
    const int c = slot ^ (row & 7);
    wgp[p] = (const char*)wt + (size_t)(n0 + row) * 9216 + (c << 4);
    wlp0[p] = ldsW0 + idx * 16;
    wlp1[p] = ldsW1 + idx * 16;
  }

  floatx4 acc[4][4] = {};

  // fragment row/site indices
  int arow[4], bsite[4];
#pragma unroll
  for (int f = 0; f < 4; ++f) arow[f] = wn + (f << 4) + ri;
#pragma unroll
  for (int fj = 0; fj < 4; ++fj)
    bsite[fj] = ((wm >> 5) + (fj >> 1)) * 34 + ((fj & 1) << 4) + ri;

  for (int chunk = 0; chunk < 8; ++chunk) {
    const int cb = chunk << 7;
    // stage X footprint chunk + W(tap0) -> buf0 (prev readers done at the
    // barrier that ended the previous chunk's last tap)
#pragma unroll
    for (int p = 0; p < 6; ++p) ASYNC16(xgp[p] + cb, xlp[p]);
    if (tid < 96) ASYNC16(xgp[6] + cb, xlp[6]);   // tail: 1632 = 6*256+96
#pragma unroll
    for (int p = 0; p < 4; ++p) ASYNC16(wgp[p] + cb, wlp0[p]);
    __syncthreads();                     // drain vmcnt -> X + W0 visible
#pragma unroll
    for (int tap = 0; tap < NTAPS; ++tap) {
      // prefetch W(tap+1) into the other buffer (freed by last barrier)
      if (tap + 1 < NTAPS) {
        const int noff = ((tap + 1) << 10) + cb;
        if (tap & 1) {
#pragma unroll
          for (int p = 0; p < 4; ++p) ASYNC16(wgp[p] + noff, wlp0[p]);
        } else {
#pragma unroll
          for (int p = 0; p < 4; ++p) ASYNC16(wgp[p] + noff, wlp1[p]);
        }
      }
      const char* wb = (tap & 1) ? ldsW1 : ldsW0;
      const int tsite = (tap / 3) * 34 + (tap % 3);   // X site offset of tap
#pragma unroll
      for (int ks = 0; ks < 2; ++ks) {
        const int c = (ks << 2) + kg;    // 16B chunk index within row
        short8 a4[4], b4[4];
#pragma unroll
        for (int f = 0; f < 4; ++f)
          a4[f] = *(const short8*)(wb + arow[f] * 128 +
                                   ((c ^ (arow[f] & 7)) << 4));
#pragma unroll
        for (int fj = 0; fj < 4; ++fj) {
          const int srow = bsite[fj] + tsite;   // shifted site; swizzle on it
          b4[fj] = *(const short8*)(ldsX + srow * 128 + ((c ^ (srow & 7)) << 4));
        }
#pragma unroll
        for (int fi = 0; fi < 4; ++fi)
#pragma unroll
          for (int fj = 0; fj < 4; ++fj)
            acc[fi][fj] = __builtin_amdgcn_mfma_f32_16x16x32_bf16(
                a4[fi], b4[fj], acc[fi][fj], 0, 0, 0);
      }
      __syncthreads();   // readers of wb & (last tap) X done; W(t+1) drained
    }
  }

  // ---- epilogue: +bias, dense 2x2 pixel-shuffle writes, fused BN stats ----
  // D layout: col=lane&15 (m), row=quad*4+reg (n). Pair-interleaved rows:
  // frag n-row r = kg*4 + j -> co = (r_global & 511)>>1, s = j&1.
  // (j0,j1) = same co, cols 2w/2w+1 -> contiguous floatx2; (j2,j3) = co+1.
  // Output row parity: P0 (bn<4) -> even rows; P1 -> odd rows.
  const int quad = kg, colL = ri;
  const int dh6 = (bn >> 2) << 6;       // +64 floats for odd output rows
#pragma unroll
  for (int fi = 0; fi < 4; ++fi) {
    const int rbase = n0 + wn + (fi << 4) + (quad << 2);   // global row', j=0..3
    const floatx4 bv = *(const floatx4*)(bias + rbase);
    const int co = (rbase & 511) >> 1;
    float sA = 0.f, s2A = 0.f, sB = 0.f, s2B = 0.f;
    float* ob = out + (((size_t)(n_img * 256 + co)) << 12) + dh6;
#pragma unroll
    for (int fj = 0; fj < 4; ++fj) {
      const int mb = wm + (fj << 4) + colL;       // m within block
      const int h = h0p + (mb >> 5), w = mb & 31; // global h (0..31)
      const float v0 = acc[fi][fj][0] + bv[0];
      const float v1 = acc[fi][fj][1] + bv[1];
      const float v2 = acc[fi][fj][2] + bv[2];
      const float v3 = acc[fi][fj][3] + bv[3];
      sA += v0 + v1;
      s2A += v0 * v0 + v1 * v1;
      sB += v2 + v3;
      s2B += v2 * v2 + v3 * v3;
      float* p = ob + (h << 7) + (w << 1);        // row 2h(+dh), col 2w
      floatx2 eA = {v0, v1};
      floatx2 eB = {v2, v3};
      *(floatx2*)p = eA;                           // co
      *(floatx2*)(p + 4096) = eB;                  // co+1
    }
#pragma unroll
    for (int off = 1; off < 16; off <<= 1) {
      sA += __shfl_xor(sA, off);
      s2A += __shfl_xor(s2A, off);
      sB += __shfl_xor(sB, off);
      s2B += __shfl_xor(s2B, off);
    }
    if (colL == 0) {
      atomicAdd(&stats[co], sA);
      atomicAdd(&stats[256 + co], s2A);
      atomicAdd(&stats[co + 1], sB);
      atomicAdd(&stats[256 + co + 1], s2B);
    }
  }
}

__global__ __launch_bounds__(256) void gemm_kernel(
    const ushort_t* __restrict__ xt, const ushort_t* __restrict__ wt,
    const float* __restrict__ bias, float* __restrict__ out,
    float* __restrict__ stats) {
  // LDS declared once, shared by both instantiations (58,880 B total).
  __shared__ char ldsX[NSITES * 128];    // 26,112 B
  __shared__ char ldsW[2][128 * 128];    // 2 x 16,384 B
  if ((blockIdx.x & 7) < 4)
    gemm_body<9>(xt, wt, bias, out, stats, ldsX, ldsW[0], ldsW[1]);
  else
    gemm_body<6>(xt, wt, bias, out, stats, ldsX, ldsW[0], ldsW[1]);
}

// -------------------------------------------------------------- bn_apply ---
__global__ __launch_bounds__(256) void bn_apply(
    float* __restrict__ y, const float* __restrict__ stats,
    const float* __restrict__ gamma, const float* __restrict__ beta) {
  const int b = blockIdx.x;
  const int co = b & 255;
  const int t = threadIdx.x;
  const float mean = stats[co] * (1.f / 65536.f);
  const float var = stats[256 + co] * (1.f / 65536.f) - mean * mean;
  const float rstd = rsqrtf(var + 1e-5f);
  const float scale = rstd * gamma[co];
  const float shift = beta[co] - mean * scale;
  float* p = y + (size_t)b * 4096;
#pragma unroll
  for (int it = 0; it < 4; ++it) {
    floatx4* q = (floatx4*)(p + (it * 256 + t) * 4);
    floatx4 v = *q;
#pragma unroll
    for (int e = 0; e < 4; ++e) v[e] = fmaxf(v[e] * scale + shift, 0.f);
    *q = v;
  }
}

// ---------------------------------------------------------------- launch ---
extern "C" void kernel_launch(void* const* d_in, const int* in_sizes, int n_in,
                              void* d_out, int out_size, void* d_ws,
                              size_t ws_size, hipStream_t stream) {
  const float* x  = (const float*)d_in[0];
  const float* w1 = (const float*)d_in[1];
  const float* b1 = (const float*)d_in[2];
  const float* w2 = (const float*)d_in[3];
  const float* b2 = (const float*)d_in[4];
  const float* w3 = (const float*)d_in[5];
  const float* b3 = (const float*)d_in[6];
  const float* w4 = (const float*)d_in[7];
  const float* b4 = (const float*)d_in[8];
  const float* gamma = (const float*)d_in[9];
  const float* beta  = (const float*)d_in[10];
  float* out = (float*)d_out;

  char* ws = (char*)d_ws;
  ushort_t* xt   = (ushort_t*)(ws + XT_OFF);
  ushort_t* wt   = (ushort_t*)(ws + WT_OFF);
  float*    bias = (float*)(ws + BIAS_OFF);
  float*    st   = (float*)(ws + STATS_OFF);

  zero_stats<<<1, 512, 0, stream>>>(st);
  prep_x<<<16 * 34, 256, 0, stream>>>(x, xt);
  prep_w<<<1024, 256, 0, stream>>>(w1, w2, w3, w4, b1, b2, b3, b4, wt, bias);
  gemm_kernel<<<1024, 256, 0, stream>>>(xt, wt, bias, out, st);
  bn_apply<<<4096, 256, 0, stream>>>(out, st, gamma, beta);
}